// Round 1
// baseline (1203.526 us; speedup 1.0000x reference)
//
#include <hip/hip_runtime.h>
#include <math.h>

#define IN_F   50
#define HID    256
#define OUT_F  121
#define N_LAYERS 4

// ---------------- lin0: x0 = relu(x @ lin0_w + b); h = x0 ----------------
__global__ void lin0_kernel(const float* __restrict__ x, const float* __restrict__ w,
                            const float* __restrict__ b, float* __restrict__ x0,
                            float* __restrict__ h, int n) {
    __shared__ float xs[IN_F];
    int node = blockIdx.x;
    int t = threadIdx.x;              // 256 threads, one per output feature
    if (t < IN_F) xs[t] = x[(size_t)node * IN_F + t];
    __syncthreads();
    float acc = b[t];
#pragma unroll
    for (int k = 0; k < IN_F; ++k)
        acc = fmaf(xs[k], w[k * HID + t], acc);
    acc = fmaxf(acc, 0.f);
    size_t idx = (size_t)node * HID + t;
    x0[idx] = acc;
    h[idx]  = acc;
}

// ---------------- CSR build ----------------
__global__ void hist_kernel(const int* __restrict__ dst, int* __restrict__ counts, int E) {
    int e = blockIdx.x * blockDim.x + threadIdx.x;
    if (e < E) atomicAdd(&counts[dst[e]], 1);
}

__global__ void scan_kernel(const int* __restrict__ counts, int* __restrict__ row_ptr,
                            int* __restrict__ cursor, int n) {
    __shared__ int sdata[1024];
    __shared__ int carry_s;
    int t = threadIdx.x;
    if (t == 0) carry_s = 0;
    __syncthreads();
    for (int base = 0; base < n; base += 1024) {
        int i = base + t;
        int v = (i < n) ? counts[i] : 0;
        sdata[t] = v;
        __syncthreads();
        for (int off = 1; off < 1024; off <<= 1) {
            int tmp = (t >= off) ? sdata[t - off] : 0;
            __syncthreads();
            sdata[t] += tmp;
            __syncthreads();
        }
        int excl = carry_s + sdata[t] - v;   // exclusive prefix including carry
        if (i < n) { row_ptr[i] = excl; cursor[i] = excl; }
        __syncthreads();
        if (t == 1023) carry_s += sdata[1023];
        __syncthreads();
    }
    if (t == 0) row_ptr[n] = carry_s;
}

__global__ void scatter_kernel(const int* __restrict__ src, const int* __restrict__ dst,
                               const float* __restrict__ ew, int* __restrict__ cursor,
                               int* __restrict__ col, float* __restrict__ wv, int E) {
    int e = blockIdx.x * blockDim.x + threadIdx.x;
    if (e < E) {
        int d = dst[e];
        int pos = atomicAdd(&cursor[d], 1);
        col[pos] = src[e];
        wv[pos] = ew[e];
    }
}

// ---------------- SpMM + alpha mix: s = 0.9*agg + 0.1*x0 ----------------
__global__ void spmm_mix_kernel(const int* __restrict__ row_ptr, const int* __restrict__ col,
                                const float* __restrict__ wv, const float* __restrict__ h,
                                const float* __restrict__ x0, float* __restrict__ s, int n) {
    int node = blockIdx.x;
    int f = threadIdx.x;              // 256 threads, one per feature
    int beg = row_ptr[node], end = row_ptr[node + 1];
    float acc = 0.f;
    for (int e = beg; e < end; ++e) {
        int c = col[e];
        float we = wv[e];
        acc = fmaf(we, h[(size_t)c * HID + f], acc);
    }
    size_t idx = (size_t)node * HID + f;
    s[idx] = 0.9f * acc + 0.1f * x0[idx];
}

// ---------------- fused GEMM layer: h = relu((1-b)*s + b*(s@W) + h) ----------------
#define BM 64
#define BN 64
#define BK 16
__global__ __launch_bounds__(256) void gemm_layer_kernel(
        const float* __restrict__ s, const float* __restrict__ W,
        float* __restrict__ h, float omb, float beta, int M) {
    __shared__ float As[BK][BM + 4];   // As[k][m]
    __shared__ float Bs[BK][BN + 4];   // Bs[k][n]
    int bm = blockIdx.x * BM, bn = blockIdx.y * BN;
    int tid = threadIdx.x;
    int tx = tid & 15, ty = tid >> 4;  // 16x16 thread grid, 4x4 micro-tile
    float acc[4][4] = {};

    for (int k0 = 0; k0 < HID; k0 += BK) {
#pragma unroll
        for (int i = 0; i < 4; ++i) {           // A: 64 rows x 16 k
            int idx = tid + i * 256;
            int row = idx >> 4;
            int kk = idx & 15;
            int gr = bm + row;
            As[kk][row] = (gr < M) ? s[(size_t)gr * HID + k0 + kk] : 0.f;
        }
#pragma unroll
        for (int i = 0; i < 4; ++i) {           // B: 16 k x 64 cols
            int idx = tid + i * 256;
            int kk = idx >> 6;
            int cc = idx & 63;
            Bs[kk][cc] = W[(size_t)(k0 + kk) * HID + bn + cc];
        }
        __syncthreads();
#pragma unroll
        for (int kk = 0; kk < BK; ++kk) {
            float4 a = *reinterpret_cast<const float4*>(&As[kk][ty * 4]);
            float4 b = *reinterpret_cast<const float4*>(&Bs[kk][tx * 4]);
            float av[4] = {a.x, a.y, a.z, a.w};
            float bv[4] = {b.x, b.y, b.z, b.w};
#pragma unroll
            for (int i = 0; i < 4; ++i)
#pragma unroll
                for (int j = 0; j < 4; ++j)
                    acc[i][j] = fmaf(av[i], bv[j], acc[i][j]);
        }
        __syncthreads();
    }

#pragma unroll
    for (int i = 0; i < 4; ++i) {
        int row = bm + ty * 4 + i;
        if (row >= M) continue;
#pragma unroll
        for (int j = 0; j < 4; ++j) {
            int cc = bn + tx * 4 + j;
            size_t idx = (size_t)row * HID + cc;
            float sv = s[idx];
            float hv = h[idx];
            h[idx] = fmaxf(omb * sv + beta * acc[i][j] + hv, 0.f);
        }
    }
}

// ---------------- lin1: out = h @ lin1_w + b ----------------
__global__ void lin1_kernel(const float* __restrict__ h, const float* __restrict__ w,
                            const float* __restrict__ b, float* __restrict__ out, int n) {
    __shared__ float hs[HID];
    int node = blockIdx.x;
    int t = threadIdx.x;              // 128 threads
    hs[t] = h[(size_t)node * HID + t];
    hs[t + 128] = h[(size_t)node * HID + t + 128];
    __syncthreads();
    if (t < OUT_F) {
        float acc = b[t];
#pragma unroll 8
        for (int k = 0; k < HID; ++k)
            acc = fmaf(hs[k], w[k * OUT_F + t], acc);
        out[(size_t)node * OUT_F + t] = acc;
    }
}

extern "C" void kernel_launch(void* const* d_in, const int* in_sizes, int n_in,
                              void* d_out, int out_size, void* d_ws, size_t ws_size,
                              hipStream_t stream) {
    const float* x      = (const float*)d_in[0];
    const int*   ei     = (const int*)d_in[1];    // [2, E] int32 per harness convention
    const float* ew     = (const float*)d_in[2];
    const float* lin0_w = (const float*)d_in[3];
    const float* lin0_b = (const float*)d_in[4];
    const float* W      = (const float*)d_in[5];
    const float* lin1_w = (const float*)d_in[6];
    const float* lin1_b = (const float*)d_in[7];
    float* out = (float*)d_out;

    int N = in_sizes[0] / IN_F;
    int E = in_sizes[2];
    const int* src = ei;
    const int* dst = ei + E;

    char* ws = (char*)d_ws;
    float* x0      = (float*)ws; ws += (size_t)N * HID * 4;
    float* h       = (float*)ws; ws += (size_t)N * HID * 4;
    float* s       = (float*)ws; ws += (size_t)N * HID * 4;
    int*   row_ptr = (int*)ws;   ws += (size_t)(N + 1) * 4;
    int*   counts  = (int*)ws;   ws += (size_t)N * 4;
    int*   cursor  = (int*)ws;   ws += (size_t)N * 4;
    int*   col     = (int*)ws;   ws += (size_t)E * 4;
    float* wv      = (float*)ws; ws += (size_t)E * 4;

    // CSR build (dst-sorted), rebuilt every call (deterministic work)
    hipMemsetAsync(counts, 0, (size_t)N * 4, stream);
    hist_kernel<<<(E + 255) / 256, 256, 0, stream>>>(dst, counts, E);
    scan_kernel<<<1, 1024, 0, stream>>>(counts, row_ptr, cursor, N);
    scatter_kernel<<<(E + 255) / 256, 256, 0, stream>>>(src, dst, ew, cursor, col, wv, E);

    lin0_kernel<<<N, HID, 0, stream>>>(x, lin0_w, lin0_b, x0, h, N);

    for (int l = 0; l < N_LAYERS; ++l) {
        float beta = logf(0.5f / (float)(l + 1) + 1.0f);
        spmm_mix_kernel<<<N, HID, 0, stream>>>(row_ptr, col, wv, h, x0, s, N);
        dim3 grid((N + BM - 1) / BM, HID / BN);
        gemm_layer_kernel<<<grid, 256, 0, stream>>>(s, W + (size_t)l * HID * HID, h,
                                                    1.0f - beta, beta, N);
    }

    lin1_kernel<<<N, 128, 0, stream>>>(h, lin1_w, lin1_b, out, N);
}

// Round 2
// 738.550 us; speedup vs baseline: 1.6296x; 1.6296x over previous
//
#include <hip/hip_runtime.h>
#include <math.h>

#define IN_F   50
#define HID    256
#define OUT_F  121
#define N_LAYERS 4

typedef __attribute__((ext_vector_type(8))) short short8;
typedef __attribute__((ext_vector_type(4))) float f32x4;

#define GLOBAL_AS __attribute__((address_space(1)))
#define LDS_AS    __attribute__((address_space(3)))

__device__ __forceinline__ ushort f2bf(float f) {
    union { float f; unsigned u; } c; c.f = f;
    unsigned u = c.u;
    u += 0x7fffu + ((u >> 16) & 1u);
    return (ushort)(u >> 16);
}

// ---------------- lin0: x0 = relu(x @ lin0_w + b); h = x0 (4 nodes/block) ----------------
__global__ __launch_bounds__(256) void lin0_kernel(
        const float* __restrict__ x, const float* __restrict__ w,
        const float* __restrict__ b, float* __restrict__ x0,
        float* __restrict__ h, int n) {
    __shared__ float xs[4][IN_F];
    int node0 = blockIdx.x * 4;
    int t = threadIdx.x;              // 256 threads, one per output feature
    if (t < 4 * IN_F) {
        int j = t / IN_F, k = t % IN_F;
        int nd = node0 + j;
        xs[j][k] = (nd < n) ? x[(size_t)nd * IN_F + k] : 0.f;
    }
    __syncthreads();
    float bias = b[t];
    float a0 = bias, a1 = bias, a2 = bias, a3 = bias;
#pragma unroll
    for (int k = 0; k < IN_F; ++k) {
        float wk = w[k * HID + t];
        a0 = fmaf(xs[0][k], wk, a0);
        a1 = fmaf(xs[1][k], wk, a1);
        a2 = fmaf(xs[2][k], wk, a2);
        a3 = fmaf(xs[3][k], wk, a3);
    }
    float r[4] = {fmaxf(a0, 0.f), fmaxf(a1, 0.f), fmaxf(a2, 0.f), fmaxf(a3, 0.f)};
#pragma unroll
    for (int j = 0; j < 4; ++j) {
        int nd = node0 + j;
        if (nd < n) {
            size_t idx = (size_t)nd * HID + t;
            x0[idx] = r[j];
            h[idx]  = r[j];
        }
    }
}

// ---------------- CSR build ----------------
__global__ void hist_kernel(const int* __restrict__ dst, int* __restrict__ counts, int E) {
    int e = blockIdx.x * blockDim.x + threadIdx.x;
    if (e < E) atomicAdd(&counts[dst[e]], 1);
}

__global__ void scan_phase1(const int* __restrict__ counts, int* __restrict__ row_ptr,
                            int* __restrict__ bsum, int n) {
    __shared__ int sd[1024];
    int t = threadIdx.x;
    int i = blockIdx.x * 1024 + t;
    int v = (i < n) ? counts[i] : 0;
    sd[t] = v;
    __syncthreads();
    for (int off = 1; off < 1024; off <<= 1) {
        int tmp = (t >= off) ? sd[t - off] : 0;
        __syncthreads();
        sd[t] += tmp;
        __syncthreads();
    }
    if (i < n) row_ptr[i] = sd[t] - v;     // block-local exclusive
    if (t == 1023) bsum[blockIdx.x] = sd[1023];
}

__global__ void scan_phase2(int* __restrict__ bsum, int nb) {
    __shared__ int sd[64];
    int t = threadIdx.x;                   // 64 threads, nb <= 64
    int v = (t < nb) ? bsum[t] : 0;
    sd[t] = v;
    __syncthreads();
    for (int off = 1; off < 64; off <<= 1) {
        int tmp = (t >= off) ? sd[t - off] : 0;
        __syncthreads();
        sd[t] += tmp;
        __syncthreads();
    }
    if (t < nb) bsum[t] = sd[t] - v;       // exclusive
    if (t == nb - 1) bsum[nb] = sd[t];     // total
}

__global__ void scan_phase3(int* __restrict__ row_ptr, int* __restrict__ cursor,
                            const int* __restrict__ bsum, int n, int nb) {
    int i = blockIdx.x * 1024 + threadIdx.x;
    if (i < n) {
        int v = row_ptr[i] + bsum[blockIdx.x];
        row_ptr[i] = v;
        cursor[i]  = v;
    }
    if (i == n - 1) row_ptr[n] = bsum[nb];
}

__global__ void scatter_kernel(const int* __restrict__ src, const int* __restrict__ dst,
                               const float* __restrict__ ew, int* __restrict__ cursor,
                               int* __restrict__ col, float* __restrict__ wv, int E) {
    int e = blockIdx.x * blockDim.x + threadIdx.x;
    if (e < E) {
        int d = dst[e];
        int pos = atomicAdd(&cursor[d], 1);
        col[pos] = src[e];
        wv[pos] = ew[e];
    }
}

// ---------------- weight transpose+convert: Wt[l][n][k] = bf16(W[l][k][n]) ----------------
__global__ void convert_w_kernel(const float* __restrict__ W, ushort* __restrict__ Wt) {
    int n = blockIdx.x, l = blockIdx.y, k = threadIdx.x;
    float v = W[(size_t)l * HID * HID + (size_t)k * HID + n];
    Wt[(size_t)l * HID * HID + (size_t)n * HID + k] = f2bf(v);
}

__global__ void convert_w1_kernel(const float* __restrict__ w1, ushort* __restrict__ Wt1) {
    int n = blockIdx.x;                    // 0..127 (pad beyond OUT_F with 0)
    int k = threadIdx.x;                   // 0..255
    float v = (n < OUT_F) ? w1[(size_t)k * OUT_F + n] : 0.f;
    Wt1[(size_t)n * HID + k] = f2bf(v);
}

// ---------------- SpMM + alpha mix: s = 0.9*agg + 0.1*x0 (also bf16 copy) ----------------
__global__ __launch_bounds__(256) void spmm_mix_kernel(
        const int* __restrict__ row_ptr, const int* __restrict__ col,
        const float* __restrict__ wv, const float* __restrict__ h,
        const float* __restrict__ x0, float* __restrict__ s,
        ushort* __restrict__ s_bf, int n) {
    int node = blockIdx.x;
    int f = threadIdx.x;
    int beg = row_ptr[node], end = row_ptr[node + 1];
    float acc = 0.f;
    for (int e = beg; e < end; ++e) {
        int c = col[e];
        float we = wv[e];
        acc = fmaf(we, h[(size_t)c * HID + f], acc);
    }
    size_t idx = (size_t)node * HID + f;
    float sv = 0.9f * acc + 0.1f * x0[idx];
    s[idx] = sv;
    s_bf[idx] = f2bf(sv);
}

// ---------------- MFMA layer GEMM: h = relu((1-b)*s + b*(s@W) + h) ----------------
// A = s_bf [M][256], B = Wt[l] [256 n][256 k] (pre-transposed), 128x128 tile, 4 waves.
// LDS layout [BK/8][128][8] bf16: linear for global_load_lds, conflict-free ds_read_b128.
__global__ __launch_bounds__(256) void gemm_mfma_layer(
        const ushort* __restrict__ s_bf, const ushort* __restrict__ wt,
        const float* __restrict__ s, float* __restrict__ h, ushort* __restrict__ h_bf,
        float omb, float beta, int M, int write_hbf) {
    __shared__ ushort As[4][128][8];   // 8 KB
    __shared__ ushort Bs[4][128][8];   // 8 KB
    int tid = threadIdx.x;
    int wave = tid >> 6;
    int lane = tid & 63;
    int r16 = lane & 15, q = lane >> 4;
    int bm = blockIdx.x * 128;
    int bn = blockIdx.y * 128;
    int wm = (wave >> 1) * 64, wn = (wave & 1) * 64;

    f32x4 acc[4][4] = {};

    int srow = tid & 127;
    int koff0 = tid >> 7;              // 0 or 1
    int arow = bm + srow; if (arow >= M) arow = M - 1;
    const ushort* aptr = s_bf + (size_t)arow * HID;
    const ushort* bptr = wt + (size_t)(bn + srow) * HID;
    char* AsB = (char*)&As[0][0][0];
    char* BsB = (char*)&Bs[0][0][0];
    int woff = wave * 1024;            // per-wave lds offset within each 4KB half

    const short8* As8 = (const short8*)&As[0][0][0];
    const short8* Bs8 = (const short8*)&Bs[0][0][0];

    for (int k0 = 0; k0 < HID; k0 += 32) {
        __builtin_amdgcn_global_load_lds((const GLOBAL_AS void*)(aptr + k0 + koff0 * 8),
                                         (LDS_AS void*)(AsB + woff), 16, 0, 0);
        __builtin_amdgcn_global_load_lds((const GLOBAL_AS void*)(aptr + k0 + (koff0 + 2) * 8),
                                         (LDS_AS void*)(AsB + 4096 + woff), 16, 0, 0);
        __builtin_amdgcn_global_load_lds((const GLOBAL_AS void*)(bptr + k0 + koff0 * 8),
                                         (LDS_AS void*)(BsB + woff), 16, 0, 0);
        __builtin_amdgcn_global_load_lds((const GLOBAL_AS void*)(bptr + k0 + (koff0 + 2) * 8),
                                         (LDS_AS void*)(BsB + 4096 + woff), 16, 0, 0);
        __syncthreads();

        short8 av[4], bv[4];
#pragma unroll
        for (int mf = 0; mf < 4; ++mf)
            av[mf] = As8[q * 128 + wm + mf * 16 + r16];
#pragma unroll
        for (int nf = 0; nf < 4; ++nf)
            bv[nf] = Bs8[q * 128 + wn + nf * 16 + r16];
#pragma unroll
        for (int mf = 0; mf < 4; ++mf)
#pragma unroll
            for (int nf = 0; nf < 4; ++nf)
                acc[mf][nf] = __builtin_amdgcn_mfma_f32_16x16x32_bf16(av[mf], bv[nf], acc[mf][nf], 0, 0, 0);
        __syncthreads();
    }

#pragma unroll
    for (int mf = 0; mf < 4; ++mf) {
#pragma unroll
        for (int j = 0; j < 4; ++j) {
            int row = bm + wm + mf * 16 + q * 4 + j;
            if (row >= M) continue;
#pragma unroll
            for (int nf = 0; nf < 4; ++nf) {
                int c = bn + wn + nf * 16 + r16;
                size_t idx = (size_t)row * HID + c;
                float v = fmaxf(omb * s[idx] + beta * acc[mf][nf][j] + h[idx], 0.f);
                h[idx] = v;
                if (write_hbf) h_bf[idx] = f2bf(v);
            }
        }
    }
}

// ---------------- MFMA lin1: out = h @ lin1_w + b ----------------
__global__ __launch_bounds__(256) void lin1_mfma(
        const ushort* __restrict__ h_bf, const ushort* __restrict__ wt1,
        const float* __restrict__ b, float* __restrict__ out, int M) {
    __shared__ ushort As[4][128][8];
    __shared__ ushort Bs[4][128][8];
    int tid = threadIdx.x;
    int wave = tid >> 6;
    int lane = tid & 63;
    int r16 = lane & 15, q = lane >> 4;
    int bm = blockIdx.x * 128;
    int wm = (wave >> 1) * 64, wn = (wave & 1) * 64;

    f32x4 acc[4][4] = {};

    int srow = tid & 127;
    int koff0 = tid >> 7;
    int arow = bm + srow; if (arow >= M) arow = M - 1;
    const ushort* aptr = h_bf + (size_t)arow * HID;
    const ushort* bptr = wt1 + (size_t)srow * HID;
    char* AsB = (char*)&As[0][0][0];
    char* BsB = (char*)&Bs[0][0][0];
    int woff = wave * 1024;

    const short8* As8 = (const short8*)&As[0][0][0];
    const short8* Bs8 = (const short8*)&Bs[0][0][0];

    for (int k0 = 0; k0 < HID; k0 += 32) {
        __builtin_amdgcn_global_load_lds((const GLOBAL_AS void*)(aptr + k0 + koff0 * 8),
                                         (LDS_AS void*)(AsB + woff), 16, 0, 0);
        __builtin_amdgcn_global_load_lds((const GLOBAL_AS void*)(aptr + k0 + (koff0 + 2) * 8),
                                         (LDS_AS void*)(AsB + 4096 + woff), 16, 0, 0);
        __builtin_amdgcn_global_load_lds((const GLOBAL_AS void*)(bptr + k0 + koff0 * 8),
                                         (LDS_AS void*)(BsB + woff), 16, 0, 0);
        __builtin_amdgcn_global_load_lds((const GLOBAL_AS void*)(bptr + k0 + (koff0 + 2) * 8),
                                         (LDS_AS void*)(BsB + 4096 + woff), 16, 0, 0);
        __syncthreads();

        short8 av[4], bv[4];
#pragma unroll
        for (int mf = 0; mf < 4; ++mf)
            av[mf] = As8[q * 128 + wm + mf * 16 + r16];
#pragma unroll
        for (int nf = 0; nf < 4; ++nf)
            bv[nf] = Bs8[q * 128 + wn + nf * 16 + r16];
#pragma unroll
        for (int mf = 0; mf < 4; ++mf)
#pragma unroll
            for (int nf = 0; nf < 4; ++nf)
                acc[mf][nf] = __builtin_amdgcn_mfma_f32_16x16x32_bf16(av[mf], bv[nf], acc[mf][nf], 0, 0, 0);
        __syncthreads();
    }

#pragma unroll
    for (int mf = 0; mf < 4; ++mf) {
#pragma unroll
        for (int j = 0; j < 4; ++j) {
            int row = bm + wm + mf * 16 + q * 4 + j;
            if (row >= M) continue;
#pragma unroll
            for (int nf = 0; nf < 4; ++nf) {
                int c = wn + nf * 16 + r16;
                if (c < OUT_F)
                    out[(size_t)row * OUT_F + c] = acc[mf][nf][j] + b[c];
            }
        }
    }
}

extern "C" void kernel_launch(void* const* d_in, const int* in_sizes, int n_in,
                              void* d_out, int out_size, void* d_ws, size_t ws_size,
                              hipStream_t stream) {
    const float* x      = (const float*)d_in[0];
    const int*   ei     = (const int*)d_in[1];
    const float* ew     = (const float*)d_in[2];
    const float* lin0_w = (const float*)d_in[3];
    const float* lin0_b = (const float*)d_in[4];
    const float* W      = (const float*)d_in[5];
    const float* lin1_w = (const float*)d_in[6];
    const float* lin1_b = (const float*)d_in[7];
    float* out = (float*)d_out;

    int N = in_sizes[0] / IN_F;
    int E = in_sizes[2];
    const int* src = ei;
    const int* dst = ei + E;

    char* ws = (char*)d_ws;
    float*  x0      = (float*)ws;  ws += (size_t)N * HID * 4;
    float*  h       = (float*)ws;  ws += (size_t)N * HID * 4;
    float*  s       = (float*)ws;  ws += (size_t)N * HID * 4;
    ushort* s_bf    = (ushort*)ws; ws += (size_t)N * HID * 2;
    ushort* h_bf    = (ushort*)ws; ws += (size_t)N * HID * 2;
    ushort* Wt      = (ushort*)ws; ws += (size_t)N_LAYERS * HID * HID * 2;
    ushort* Wt1     = (ushort*)ws; ws += (size_t)128 * HID * 2;
    int*    row_ptr = (int*)ws;    ws += (size_t)(N + 1) * 4;
    int*    counts  = (int*)ws;    ws += (size_t)N * 4;
    int*    cursor  = (int*)ws;    ws += (size_t)N * 4;
    int*    bsum    = (int*)ws;    ws += (size_t)128 * 4;
    int*    col     = (int*)ws;    ws += (size_t)E * 4;
    float*  wv      = (float*)ws;  ws += (size_t)E * 4;

    int nb = (N + 1023) / 1024;

    // CSR build
    hipMemsetAsync(counts, 0, (size_t)N * 4, stream);
    hist_kernel<<<(E + 255) / 256, 256, 0, stream>>>(dst, counts, E);
    scan_phase1<<<nb, 1024, 0, stream>>>(counts, row_ptr, bsum, N);
    scan_phase2<<<1, 64, 0, stream>>>(bsum, nb);
    scan_phase3<<<nb, 1024, 0, stream>>>(row_ptr, cursor, bsum, N, nb);
    scatter_kernel<<<(E + 255) / 256, 256, 0, stream>>>(src, dst, ew, cursor, col, wv, E);

    // weight conversion
    convert_w_kernel<<<dim3(HID, N_LAYERS), HID, 0, stream>>>(W, Wt);
    convert_w1_kernel<<<128, HID, 0, stream>>>(lin1_w, Wt1);

    lin0_kernel<<<(N + 3) / 4, HID, 0, stream>>>(x, lin0_w, lin0_b, x0, h, N);

    int mblocks = (N + 127) / 128;
    for (int l = 0; l < N_LAYERS; ++l) {
        float beta = logf(0.5f / (float)(l + 1) + 1.0f);
        spmm_mix_kernel<<<N, HID, 0, stream>>>(row_ptr, col, wv, h, x0, s, s_bf, N);
        gemm_mfma_layer<<<dim3(mblocks, 2), 256, 0, stream>>>(
            s_bf, Wt + (size_t)l * HID * HID, s, h, h_bf,
            1.0f - beta, beta, N, l == N_LAYERS - 1 ? 1 : 0);
    }

    lin1_mfma<<<mblocks, 256, 0, stream>>>(h_bf, Wt1, lin1_b, out, N);
}

// Round 3
// 402.601 us; speedup vs baseline: 2.9894x; 1.8344x over previous
//
#include <hip/hip_runtime.h>
#include <math.h>

#define IN_F   50
#define HID    256
#define OUT_F  121
#define N_LAYERS 4

typedef __attribute__((ext_vector_type(8))) short short8;
typedef __attribute__((ext_vector_type(4))) float f32x4;

#define GLOBAL_AS __attribute__((address_space(1)))
#define LDS_AS    __attribute__((address_space(3)))

__device__ __forceinline__ ushort f2bf(float f) {
    union { float f; unsigned u; } c; c.f = f;
    unsigned u = c.u;
    u += 0x7fffu + ((u >> 16) & 1u);
    return (ushort)(u >> 16);
}
__device__ __forceinline__ float bf2f(ushort u) {
    union { unsigned u; float f; } c; c.u = ((unsigned)u) << 16;
    return c.f;
}

// ---------------- lin0: x0 = relu(x @ lin0_w + b); h = x0 (bf16 out, 4 nodes/block) ----
__global__ __launch_bounds__(256) void lin0_kernel(
        const float* __restrict__ x, const float* __restrict__ w,
        const float* __restrict__ b, ushort* __restrict__ x0_bf,
        ushort* __restrict__ h_bf, int n) {
    __shared__ float xs[4][IN_F];
    int node0 = blockIdx.x * 4;
    int t = threadIdx.x;
    if (t < 4 * IN_F) {
        int j = t / IN_F, k = t % IN_F;
        int nd = node0 + j;
        xs[j][k] = (nd < n) ? x[(size_t)nd * IN_F + k] : 0.f;
    }
    __syncthreads();
    float bias = b[t];
    float a0 = bias, a1 = bias, a2 = bias, a3 = bias;
#pragma unroll
    for (int k = 0; k < IN_F; ++k) {
        float wk = w[k * HID + t];
        a0 = fmaf(xs[0][k], wk, a0);
        a1 = fmaf(xs[1][k], wk, a1);
        a2 = fmaf(xs[2][k], wk, a2);
        a3 = fmaf(xs[3][k], wk, a3);
    }
    float r[4] = {fmaxf(a0, 0.f), fmaxf(a1, 0.f), fmaxf(a2, 0.f), fmaxf(a3, 0.f)};
#pragma unroll
    for (int j = 0; j < 4; ++j) {
        int nd = node0 + j;
        if (nd < n) {
            size_t idx = (size_t)nd * HID + t;
            ushort v = f2bf(r[j]);
            x0_bf[idx] = v;
            h_bf[idx]  = v;
        }
    }
}

// ---------------- CSR build ----------------
__global__ void hist_kernel(const int* __restrict__ dst, int* __restrict__ counts, int E) {
    int e = blockIdx.x * blockDim.x + threadIdx.x;
    if (e < E) atomicAdd(&counts[dst[e]], 1);
}

__global__ void scan_phase1(const int* __restrict__ counts, int* __restrict__ row_ptr,
                            int* __restrict__ bsum, int n) {
    __shared__ int sd[1024];
    int t = threadIdx.x;
    int i = blockIdx.x * 1024 + t;
    int v = (i < n) ? counts[i] : 0;
    sd[t] = v;
    __syncthreads();
    for (int off = 1; off < 1024; off <<= 1) {
        int tmp = (t >= off) ? sd[t - off] : 0;
        __syncthreads();
        sd[t] += tmp;
        __syncthreads();
    }
    if (i < n) row_ptr[i] = sd[t] - v;
    if (t == 1023) bsum[blockIdx.x] = sd[1023];
}

__global__ void scan_phase2(int* __restrict__ bsum, int nb) {
    __shared__ int sd[64];
    int t = threadIdx.x;
    int v = (t < nb) ? bsum[t] : 0;
    sd[t] = v;
    __syncthreads();
    for (int off = 1; off < 64; off <<= 1) {
        int tmp = (t >= off) ? sd[t - off] : 0;
        __syncthreads();
        sd[t] += tmp;
        __syncthreads();
    }
    if (t < nb) bsum[t] = sd[t] - v;
    if (t == nb - 1) bsum[nb] = sd[t];
}

__global__ void scan_phase3(int* __restrict__ row_ptr, int* __restrict__ cursor,
                            const int* __restrict__ bsum, int n, int nb) {
    int i = blockIdx.x * 1024 + threadIdx.x;
    if (i < n) {
        int v = row_ptr[i] + bsum[blockIdx.x];
        row_ptr[i] = v;
        cursor[i]  = v;
    }
    if (i == n - 1) row_ptr[n] = bsum[nb];
}

__global__ void scatter_kernel(const int* __restrict__ src, const int* __restrict__ dst,
                               const float* __restrict__ ew, int* __restrict__ cursor,
                               int* __restrict__ col, float* __restrict__ wv, int E) {
    int e = blockIdx.x * blockDim.x + threadIdx.x;
    if (e < E) {
        int d = dst[e];
        int pos = atomicAdd(&cursor[d], 1);
        col[pos] = src[e];
        wv[pos] = ew[e];
    }
}

// ------- weight fold+transpose+convert: Wt[l][n][k] = bf16(beta*W[l][k][n] + (1-beta)*I) -
__global__ void convert_w_kernel(const float* __restrict__ W, ushort* __restrict__ Wt) {
    int n = blockIdx.x, l = blockIdx.y, k = threadIdx.x;
    float beta = logf(0.5f / (float)(l + 1) + 1.0f);
    float v = beta * W[(size_t)l * HID * HID + (size_t)k * HID + n];
    if (k == n) v += 1.0f - beta;
    Wt[(size_t)l * HID * HID + (size_t)n * HID + k] = f2bf(v);
}

__global__ void convert_w1_kernel(const float* __restrict__ w1, ushort* __restrict__ Wt1) {
    int n = blockIdx.x;
    int k = threadIdx.x;
    float v = (n < OUT_F) ? w1[(size_t)k * OUT_F + n] : 0.f;
    Wt1[(size_t)n * HID + k] = f2bf(v);
}

// ---------------- SpMM + alpha mix: s_bf = bf16(0.9*agg + 0.1*x0), wave per node -------
__global__ __launch_bounds__(256) void spmm_mix_kernel(
        const int* __restrict__ row_ptr, const int* __restrict__ col,
        const float* __restrict__ wv, const ushort* __restrict__ h_bf,
        const ushort* __restrict__ x0_bf, ushort* __restrict__ s_bf, int n) {
    int node = (blockIdx.x * 256 + threadIdx.x) >> 6;
    if (node >= n) return;
    int lane = threadIdx.x & 63;
    int f0 = lane * 4;
    int beg = row_ptr[node], end = row_ptr[node + 1];
    float a0 = 0.f, a1 = 0.f, a2 = 0.f, a3 = 0.f;
    int e = beg;
    for (; e + 2 <= end; e += 2) {
        int c0 = col[e], c1 = col[e + 1];
        float w0 = wv[e], w1 = wv[e + 1];
        ushort4 v0 = *reinterpret_cast<const ushort4*>(&h_bf[(size_t)c0 * HID + f0]);
        ushort4 v1 = *reinterpret_cast<const ushort4*>(&h_bf[(size_t)c1 * HID + f0]);
        a0 = fmaf(w0, bf2f(v0.x), a0); a1 = fmaf(w0, bf2f(v0.y), a1);
        a2 = fmaf(w0, bf2f(v0.z), a2); a3 = fmaf(w0, bf2f(v0.w), a3);
        a0 = fmaf(w1, bf2f(v1.x), a0); a1 = fmaf(w1, bf2f(v1.y), a1);
        a2 = fmaf(w1, bf2f(v1.z), a2); a3 = fmaf(w1, bf2f(v1.w), a3);
    }
    if (e < end) {
        int c0 = col[e];
        float w0 = wv[e];
        ushort4 v0 = *reinterpret_cast<const ushort4*>(&h_bf[(size_t)c0 * HID + f0]);
        a0 = fmaf(w0, bf2f(v0.x), a0); a1 = fmaf(w0, bf2f(v0.y), a1);
        a2 = fmaf(w0, bf2f(v0.z), a2); a3 = fmaf(w0, bf2f(v0.w), a3);
    }
    size_t idx = (size_t)node * HID + f0;
    ushort4 xv = *reinterpret_cast<const ushort4*>(&x0_bf[idx]);
    ushort4 r;
    r.x = f2bf(0.9f * a0 + 0.1f * bf2f(xv.x));
    r.y = f2bf(0.9f * a1 + 0.1f * bf2f(xv.y));
    r.z = f2bf(0.9f * a2 + 0.1f * bf2f(xv.z));
    r.w = f2bf(0.9f * a3 + 0.1f * bf2f(xv.w));
    *reinterpret_cast<ushort4*>(&s_bf[idx]) = r;
}

// ---------------- MFMA layer GEMM: h_bf = relu(s @ W' + h_bf) ----------------
__global__ __launch_bounds__(256) void gemm_mfma_layer(
        const ushort* __restrict__ s_bf, const ushort* __restrict__ wt,
        ushort* __restrict__ h_bf, int M) {
    __shared__ ushort As[4][128][8];
    __shared__ ushort Bs[4][128][8];
    int tid = threadIdx.x;
    int wave = tid >> 6;
    int lane = tid & 63;
    int r16 = lane & 15, q = lane >> 4;
    int bm = blockIdx.x * 128;
    int bn = blockIdx.y * 128;
    int wm = (wave >> 1) * 64, wn = (wave & 1) * 64;

    f32x4 acc[4][4] = {};

    int srow = tid & 127;
    int koff0 = tid >> 7;
    int arow = bm + srow; if (arow >= M) arow = M - 1;
    const ushort* aptr = s_bf + (size_t)arow * HID;
    const ushort* bptr = wt + (size_t)(bn + srow) * HID;
    char* AsB = (char*)&As[0][0][0];
    char* BsB = (char*)&Bs[0][0][0];
    int woff = wave * 1024;

    const short8* As8 = (const short8*)&As[0][0][0];
    const short8* Bs8 = (const short8*)&Bs[0][0][0];

    for (int k0 = 0; k0 < HID; k0 += 32) {
        __builtin_amdgcn_global_load_lds((const GLOBAL_AS void*)(aptr + k0 + koff0 * 8),
                                         (LDS_AS void*)(AsB + woff), 16, 0, 0);
        __builtin_amdgcn_global_load_lds((const GLOBAL_AS void*)(aptr + k0 + (koff0 + 2) * 8),
                                         (LDS_AS void*)(AsB + 4096 + woff), 16, 0, 0);
        __builtin_amdgcn_global_load_lds((const GLOBAL_AS void*)(bptr + k0 + koff0 * 8),
                                         (LDS_AS void*)(BsB + woff), 16, 0, 0);
        __builtin_amdgcn_global_load_lds((const GLOBAL_AS void*)(bptr + k0 + (koff0 + 2) * 8),
                                         (LDS_AS void*)(BsB + 4096 + woff), 16, 0, 0);
        __syncthreads();

        short8 av[4], bv[4];
#pragma unroll
        for (int mf = 0; mf < 4; ++mf)
            av[mf] = As8[q * 128 + wm + mf * 16 + r16];
#pragma unroll
        for (int nf = 0; nf < 4; ++nf)
            bv[nf] = Bs8[q * 128 + wn + nf * 16 + r16];
#pragma unroll
        for (int mf = 0; mf < 4; ++mf)
#pragma unroll
            for (int nf = 0; nf < 4; ++nf)
                acc[mf][nf] = __builtin_amdgcn_mfma_f32_16x16x32_bf16(av[mf], bv[nf], acc[mf][nf], 0, 0, 0);
        __syncthreads();
    }

#pragma unroll
    for (int mf = 0; mf < 4; ++mf) {
#pragma unroll
        for (int j = 0; j < 4; ++j) {
            int row = bm + wm + mf * 16 + q * 4 + j;
            if (row >= M) continue;
#pragma unroll
            for (int nf = 0; nf < 4; ++nf) {
                int c = bn + wn + nf * 16 + r16;
                size_t idx = (size_t)row * HID + c;
                float v = fmaxf(acc[mf][nf][j] + bf2f(h_bf[idx]), 0.f);
                h_bf[idx] = f2bf(v);
            }
        }
    }
}

// ---------------- MFMA lin1: out = h @ lin1_w + b ----------------
__global__ __launch_bounds__(256) void lin1_mfma(
        const ushort* __restrict__ h_bf, const ushort* __restrict__ wt1,
        const float* __restrict__ b, float* __restrict__ out, int M) {
    __shared__ ushort As[4][128][8];
    __shared__ ushort Bs[4][128][8];
    int tid = threadIdx.x;
    int wave = tid >> 6;
    int lane = tid & 63;
    int r16 = lane & 15, q = lane >> 4;
    int bm = blockIdx.x * 128;
    int wm = (wave >> 1) * 64, wn = (wave & 1) * 64;

    f32x4 acc[4][4] = {};

    int srow = tid & 127;
    int koff0 = tid >> 7;
    int arow = bm + srow; if (arow >= M) arow = M - 1;
    const ushort* aptr = h_bf + (size_t)arow * HID;
    const ushort* bptr = wt1 + (size_t)srow * HID;
    char* AsB = (char*)&As[0][0][0];
    char* BsB = (char*)&Bs[0][0][0];
    int woff = wave * 1024;

    const short8* As8 = (const short8*)&As[0][0][0];
    const short8* Bs8 = (const short8*)&Bs[0][0][0];

    for (int k0 = 0; k0 < HID; k0 += 32) {
        __builtin_amdgcn_global_load_lds((const GLOBAL_AS void*)(aptr + k0 + koff0 * 8),
                                         (LDS_AS void*)(AsB + woff), 16, 0, 0);
        __builtin_amdgcn_global_load_lds((const GLOBAL_AS void*)(aptr + k0 + (koff0 + 2) * 8),
                                         (LDS_AS void*)(AsB + 4096 + woff), 16, 0, 0);
        __builtin_amdgcn_global_load_lds((const GLOBAL_AS void*)(bptr + k0 + koff0 * 8),
                                         (LDS_AS void*)(BsB + woff), 16, 0, 0);
        __builtin_amdgcn_global_load_lds((const GLOBAL_AS void*)(bptr + k0 + (koff0 + 2) * 8),
                                         (LDS_AS void*)(BsB + 4096 + woff), 16, 0, 0);
        __syncthreads();

        short8 av[4], bv[4];
#pragma unroll
        for (int mf = 0; mf < 4; ++mf)
            av[mf] = As8[q * 128 + wm + mf * 16 + r16];
#pragma unroll
        for (int nf = 0; nf < 4; ++nf)
            bv[nf] = Bs8[q * 128 + wn + nf * 16 + r16];
#pragma unroll
        for (int mf = 0; mf < 4; ++mf)
#pragma unroll
            for (int nf = 0; nf < 4; ++nf)
                acc[mf][nf] = __builtin_amdgcn_mfma_f32_16x16x32_bf16(av[mf], bv[nf], acc[mf][nf], 0, 0, 0);
        __syncthreads();
    }

#pragma unroll
    for (int mf = 0; mf < 4; ++mf) {
#pragma unroll
        for (int j = 0; j < 4; ++j) {
            int row = bm + wm + mf * 16 + q * 4 + j;
            if (row >= M) continue;
#pragma unroll
            for (int nf = 0; nf < 4; ++nf) {
                int c = wn + nf * 16 + r16;
                if (c < OUT_F)
                    out[(size_t)row * OUT_F + c] = acc[mf][nf][j] + b[c];
            }
        }
    }
}

extern "C" void kernel_launch(void* const* d_in, const int* in_sizes, int n_in,
                              void* d_out, int out_size, void* d_ws, size_t ws_size,
                              hipStream_t stream) {
    const float* x      = (const float*)d_in[0];
    const int*   ei     = (const int*)d_in[1];
    const float* ew     = (const float*)d_in[2];
    const float* lin0_w = (const float*)d_in[3];
    const float* lin0_b = (const float*)d_in[4];
    const float* W      = (const float*)d_in[5];
    const float* lin1_w = (const float*)d_in[6];
    const float* lin1_b = (const float*)d_in[7];
    float* out = (float*)d_out;

    int N = in_sizes[0] / IN_F;
    int E = in_sizes[2];
    const int* src = ei;
    const int* dst = ei + E;

    char* ws = (char*)d_ws;
    ushort* x0_bf   = (ushort*)ws; ws += (size_t)N * HID * 2;
    ushort* h_bf    = (ushort*)ws; ws += (size_t)N * HID * 2;
    ushort* s_bf    = (ushort*)ws; ws += (size_t)N * HID * 2;
    ushort* Wt      = (ushort*)ws; ws += (size_t)N_LAYERS * HID * HID * 2;
    ushort* Wt1     = (ushort*)ws; ws += (size_t)128 * HID * 2;
    int*    row_ptr = (int*)ws;    ws += (size_t)(N + 1) * 4;
    int*    counts  = (int*)ws;    ws += (size_t)N * 4;
    int*    cursor  = (int*)ws;    ws += (size_t)N * 4;
    int*    bsum    = (int*)ws;    ws += (size_t)128 * 4;
    int*    col     = (int*)ws;    ws += (size_t)E * 4;
    float*  wv      = (float*)ws;  ws += (size_t)E * 4;

    int nb = (N + 1023) / 1024;

    hipMemsetAsync(counts, 0, (size_t)N * 4, stream);
    hist_kernel<<<(E + 255) / 256, 256, 0, stream>>>(dst, counts, E);
    scan_phase1<<<nb, 1024, 0, stream>>>(counts, row_ptr, bsum, N);
    scan_phase2<<<1, 64, 0, stream>>>(bsum, nb);
    scan_phase3<<<nb, 1024, 0, stream>>>(row_ptr, cursor, bsum, N, nb);
    scatter_kernel<<<(E + 255) / 256, 256, 0, stream>>>(src, dst, ew, cursor, col, wv, E);

    convert_w_kernel<<<dim3(HID, N_LAYERS), HID, 0, stream>>>(W, Wt);
    convert_w1_kernel<<<128, HID, 0, stream>>>(lin1_w, Wt1);

    lin0_kernel<<<(N + 3) / 4, HID, 0, stream>>>(x, lin0_w, lin0_b, x0_bf, h_bf, N);

    int mblocks = (N + 127) / 128;
    for (int l = 0; l < N_LAYERS; ++l) {
        spmm_mix_kernel<<<(N + 3) / 4, 256, 0, stream>>>(row_ptr, col, wv, h_bf, x0_bf, s_bf, N);
        gemm_mfma_layer<<<dim3(mblocks, 2), 256, 0, stream>>>(
            s_bf, Wt + (size_t)l * HID * HID, h_bf, N);
    }

    lin1_mfma<<<mblocks, 256, 0, stream>>>(h_bf, Wt1, lin1_b, out, N);
}

// Round 4
// 352.353 us; speedup vs baseline: 3.4157x; 1.1426x over previous
//
#include <hip/hip_runtime.h>
#include <math.h>

#define IN_F   50
#define HID    256
#define OUT_F  121
#define N_LAYERS 4
#define K0PAD  64

typedef __attribute__((ext_vector_type(8))) short short8;
typedef __attribute__((ext_vector_type(4))) float f32x4;

#define GLOBAL_AS __attribute__((address_space(1)))
#define LDS_AS    __attribute__((address_space(3)))

__device__ __forceinline__ ushort f2bf(float f) {
    union { float f; unsigned u; } c; c.f = f;
    unsigned u = c.u;
    u += 0x7fffu + ((u >> 16) & 1u);
    return (ushort)(u >> 16);
}
__device__ __forceinline__ float bf2f(ushort u) {
    union { unsigned u; float f; } c; c.u = ((unsigned)u) << 16;
    return c.f;
}

// ---------------- CSR build ----------------
__global__ void hist_kernel(const int* __restrict__ dst, int* __restrict__ counts, int E) {
    int e = blockIdx.x * blockDim.x + threadIdx.x;
    if (e < E) atomicAdd(&counts[dst[e]], 1);
}

__global__ void scan_phase1(const int* __restrict__ counts, int* __restrict__ row_ptr,
                            int* __restrict__ bsum, int n) {
    __shared__ int sd[1024];
    int t = threadIdx.x;
    int i = blockIdx.x * 1024 + t;
    int v = (i < n) ? counts[i] : 0;
    sd[t] = v;
    __syncthreads();
    for (int off = 1; off < 1024; off <<= 1) {
        int tmp = (t >= off) ? sd[t - off] : 0;
        __syncthreads();
        sd[t] += tmp;
        __syncthreads();
    }
    if (i < n) row_ptr[i] = sd[t] - v;
    if (t == 1023) bsum[blockIdx.x] = sd[1023];
}

__global__ void scan_phase2(int* __restrict__ bsum, int nb) {
    __shared__ int sd[64];
    int t = threadIdx.x;
    int v = (t < nb) ? bsum[t] : 0;
    sd[t] = v;
    __syncthreads();
    for (int off = 1; off < 64; off <<= 1) {
        int tmp = (t >= off) ? sd[t - off] : 0;
        __syncthreads();
        sd[t] += tmp;
        __syncthreads();
    }
    if (t < nb) bsum[t] = sd[t] - v;
    if (t == nb - 1) bsum[nb] = sd[t];
}

__global__ void scan_phase3(int* __restrict__ row_ptr, int* __restrict__ cursor,
                            const int* __restrict__ bsum, int n, int nb) {
    int i = blockIdx.x * 1024 + threadIdx.x;
    if (i < n) {
        int v = row_ptr[i] + bsum[blockIdx.x];
        row_ptr[i] = v;
        cursor[i]  = v;
    }
    if (i == n - 1) row_ptr[n] = bsum[nb];
}

__global__ void scatter_kernel(const int* __restrict__ src, const int* __restrict__ dst,
                               const float* __restrict__ ew, int* __restrict__ cursor,
                               int* __restrict__ col, float* __restrict__ wv, int E) {
    int e = blockIdx.x * blockDim.x + threadIdx.x;
    if (e < E) {
        int d = dst[e];
        int pos = atomicAdd(&cursor[d], 1);
        col[pos] = src[e];
        wv[pos] = ew[e];
    }
}

// ---------------- conversions ----------------
__global__ void convert_x_kernel(const float* __restrict__ x, ushort* __restrict__ x_bf, int n) {
    int i = blockIdx.x * 256 + threadIdx.x;
    int nd = i >> 6, k = i & 63;
    if (nd < n) x_bf[i] = (k < IN_F) ? f2bf(x[(size_t)nd * IN_F + k]) : 0;
}

__global__ void convert_w0_kernel(const float* __restrict__ w, ushort* __restrict__ wt0) {
    int nn = blockIdx.x;                  // 0..255
    int k = threadIdx.x;                  // 0..63
    float v = (k < IN_F) ? w[(size_t)k * HID + nn] : 0.f;
    wt0[(size_t)nn * K0PAD + k] = f2bf(v);
}

// Wt[l][n][k] = bf16(beta*W[l][k][n] + (1-beta)*I)
__global__ void convert_w_kernel(const float* __restrict__ W, ushort* __restrict__ Wt) {
    int nn = blockIdx.x, l = blockIdx.y, k = threadIdx.x;
    float beta = logf(0.5f / (float)(l + 1) + 1.0f);
    float v = beta * W[(size_t)l * HID * HID + (size_t)k * HID + nn];
    if (k == nn) v += 1.0f - beta;
    Wt[(size_t)l * HID * HID + (size_t)nn * HID + k] = f2bf(v);
}

__global__ void convert_w1_kernel(const float* __restrict__ w1, ushort* __restrict__ Wt1) {
    int nn = blockIdx.x;
    int k = threadIdx.x;
    float v = (nn < OUT_F) ? w1[(size_t)k * OUT_F + nn] : 0.f;
    Wt1[(size_t)nn * HID + k] = f2bf(v);
}

// ---------------- lin0 MFMA: x0 = relu(x_bf @ Wt0^T + b), K=64 ----------------
__global__ __launch_bounds__(256) void lin0_mfma(
        const ushort* __restrict__ x_bf, const ushort* __restrict__ wt0,
        const float* __restrict__ b, ushort* __restrict__ x0_bf,
        ushort* __restrict__ h_bf, int M) {
    __shared__ ushort As[4][128][8];
    __shared__ ushort Bs[4][128][8];
    int tid = threadIdx.x;
    int wave = tid >> 6;
    int lane = tid & 63;
    int r16 = lane & 15, q = lane >> 4;
    int bm = blockIdx.x * 128;
    int bn = blockIdx.y * 128;
    int wm = (wave >> 1) * 64, wn = (wave & 1) * 64;

    f32x4 acc[4][4] = {};

    int srow = tid & 127;
    int koff0 = tid >> 7;
    int arow = bm + srow; if (arow >= M) arow = M - 1;
    const ushort* aptr = x_bf + (size_t)arow * K0PAD;
    const ushort* bptr = wt0 + (size_t)(bn + srow) * K0PAD;
    char* AsB = (char*)&As[0][0][0];
    char* BsB = (char*)&Bs[0][0][0];
    int woff = wave * 1024;

    const short8* As8 = (const short8*)&As[0][0][0];
    const short8* Bs8 = (const short8*)&Bs[0][0][0];

    for (int k0 = 0; k0 < K0PAD; k0 += 32) {
        __builtin_amdgcn_global_load_lds((const GLOBAL_AS void*)(aptr + k0 + koff0 * 8),
                                         (LDS_AS void*)(AsB + woff), 16, 0, 0);
        __builtin_amdgcn_global_load_lds((const GLOBAL_AS void*)(aptr + k0 + (koff0 + 2) * 8),
                                         (LDS_AS void*)(AsB + 4096 + woff), 16, 0, 0);
        __builtin_amdgcn_global_load_lds((const GLOBAL_AS void*)(bptr + k0 + koff0 * 8),
                                         (LDS_AS void*)(BsB + woff), 16, 0, 0);
        __builtin_amdgcn_global_load_lds((const GLOBAL_AS void*)(bptr + k0 + (koff0 + 2) * 8),
                                         (LDS_AS void*)(BsB + 4096 + woff), 16, 0, 0);
        __syncthreads();

        short8 av[4], bv[4];
#pragma unroll
        for (int mf = 0; mf < 4; ++mf)
            av[mf] = As8[q * 128 + wm + mf * 16 + r16];
#pragma unroll
        for (int nf = 0; nf < 4; ++nf)
            bv[nf] = Bs8[q * 128 + wn + nf * 16 + r16];
#pragma unroll
        for (int mf = 0; mf < 4; ++mf)
#pragma unroll
            for (int nf = 0; nf < 4; ++nf)
                acc[mf][nf] = __builtin_amdgcn_mfma_f32_16x16x32_bf16(av[mf], bv[nf], acc[mf][nf], 0, 0, 0);
        __syncthreads();
    }

#pragma unroll
    for (int mf = 0; mf < 4; ++mf) {
#pragma unroll
        for (int j = 0; j < 4; ++j) {
            int row = bm + wm + mf * 16 + q * 4 + j;
            if (row >= M) continue;
#pragma unroll
            for (int nf = 0; nf < 4; ++nf) {
                int c = bn + wn + nf * 16 + r16;
                size_t idx = (size_t)row * HID + c;
                ushort v = f2bf(fmaxf(acc[mf][nf][j] + b[c], 0.f));
                x0_bf[idx] = v;
                h_bf[idx]  = v;
            }
        }
    }
}

// ---------------- SpMM + alpha mix: s_bf = bf16(0.9*agg + 0.1*x0), wave/node, 4-deep --
__global__ __launch_bounds__(256) void spmm_mix_kernel(
        const int* __restrict__ row_ptr, const int* __restrict__ col,
        const float* __restrict__ wv, const ushort* __restrict__ h_bf,
        const ushort* __restrict__ x0_bf, ushort* __restrict__ s_bf, int n) {
    int node = (blockIdx.x * 256 + threadIdx.x) >> 6;
    if (node >= n) return;
    int lane = threadIdx.x & 63;
    int f0 = lane * 4;
    int beg = row_ptr[node], end = row_ptr[node + 1];
    float a0 = 0.f, a1 = 0.f, a2 = 0.f, a3 = 0.f;
    int e = beg;
    for (; e + 4 <= end; e += 4) {
        int c0 = col[e], c1 = col[e + 1], c2 = col[e + 2], c3 = col[e + 3];
        float w0 = wv[e], w1 = wv[e + 1], w2 = wv[e + 2], w3 = wv[e + 3];
        ushort4 v0 = *reinterpret_cast<const ushort4*>(&h_bf[(size_t)c0 * HID + f0]);
        ushort4 v1 = *reinterpret_cast<const ushort4*>(&h_bf[(size_t)c1 * HID + f0]);
        ushort4 v2 = *reinterpret_cast<const ushort4*>(&h_bf[(size_t)c2 * HID + f0]);
        ushort4 v3 = *reinterpret_cast<const ushort4*>(&h_bf[(size_t)c3 * HID + f0]);
        a0 = fmaf(w0, bf2f(v0.x), a0); a1 = fmaf(w0, bf2f(v0.y), a1);
        a2 = fmaf(w0, bf2f(v0.z), a2); a3 = fmaf(w0, bf2f(v0.w), a3);
        a0 = fmaf(w1, bf2f(v1.x), a0); a1 = fmaf(w1, bf2f(v1.y), a1);
        a2 = fmaf(w1, bf2f(v1.z), a2); a3 = fmaf(w1, bf2f(v1.w), a3);
        a0 = fmaf(w2, bf2f(v2.x), a0); a1 = fmaf(w2, bf2f(v2.y), a1);
        a2 = fmaf(w2, bf2f(v2.z), a2); a3 = fmaf(w2, bf2f(v2.w), a3);
        a0 = fmaf(w3, bf2f(v3.x), a0); a1 = fmaf(w3, bf2f(v3.y), a1);
        a2 = fmaf(w3, bf2f(v3.z), a2); a3 = fmaf(w3, bf2f(v3.w), a3);
    }
    if (e + 2 <= end) {
        int c0 = col[e], c1 = col[e + 1];
        float w0 = wv[e], w1 = wv[e + 1];
        ushort4 v0 = *reinterpret_cast<const ushort4*>(&h_bf[(size_t)c0 * HID + f0]);
        ushort4 v1 = *reinterpret_cast<const ushort4*>(&h_bf[(size_t)c1 * HID + f0]);
        a0 = fmaf(w0, bf2f(v0.x), a0); a1 = fmaf(w0, bf2f(v0.y), a1);
        a2 = fmaf(w0, bf2f(v0.z), a2); a3 = fmaf(w0, bf2f(v0.w), a3);
        a0 = fmaf(w1, bf2f(v1.x), a0); a1 = fmaf(w1, bf2f(v1.y), a1);
        a2 = fmaf(w1, bf2f(v1.z), a2); a3 = fmaf(w1, bf2f(v1.w), a3);
        e += 2;
    }
    if (e < end) {
        int c0 = col[e];
        float w0 = wv[e];
        ushort4 v0 = *reinterpret_cast<const ushort4*>(&h_bf[(size_t)c0 * HID + f0]);
        a0 = fmaf(w0, bf2f(v0.x), a0); a1 = fmaf(w0, bf2f(v0.y), a1);
        a2 = fmaf(w0, bf2f(v0.z), a2); a3 = fmaf(w0, bf2f(v0.w), a3);
    }
    size_t idx = (size_t)node * HID + f0;
    ushort4 xv = *reinterpret_cast<const ushort4*>(&x0_bf[idx]);
    ushort4 r;
    r.x = f2bf(0.9f * a0 + 0.1f * bf2f(xv.x));
    r.y = f2bf(0.9f * a1 + 0.1f * bf2f(xv.y));
    r.z = f2bf(0.9f * a2 + 0.1f * bf2f(xv.z));
    r.w = f2bf(0.9f * a3 + 0.1f * bf2f(xv.w));
    *reinterpret_cast<ushort4*>(&s_bf[idx]) = r;
}

// ---------------- MFMA layer GEMM: h_bf = relu(s @ W' + h_bf) ----------------
__global__ __launch_bounds__(256) void gemm_mfma_layer(
        const ushort* __restrict__ s_bf, const ushort* __restrict__ wt,
        ushort* __restrict__ h_bf, int M) {
    __shared__ ushort As[4][128][8];
    __shared__ ushort Bs[4][128][8];
    int tid = threadIdx.x;
    int wave = tid >> 6;
    int lane = tid & 63;
    int r16 = lane & 15, q = lane >> 4;
    int bm = blockIdx.x * 128;
    int bn = blockIdx.y * 128;
    int wm = (wave >> 1) * 64, wn = (wave & 1) * 64;

    f32x4 acc[4][4] = {};

    int srow = tid & 127;
    int koff0 = tid >> 7;
    int arow = bm + srow; if (arow >= M) arow = M - 1;
    const ushort* aptr = s_bf + (size_t)arow * HID;
    const ushort* bptr = wt + (size_t)(bn + srow) * HID;
    char* AsB = (char*)&As[0][0][0];
    char* BsB = (char*)&Bs[0][0][0];
    int woff = wave * 1024;

    const short8* As8 = (const short8*)&As[0][0][0];
    const short8* Bs8 = (const short8*)&Bs[0][0][0];

    for (int k0 = 0; k0 < HID; k0 += 32) {
        __builtin_amdgcn_global_load_lds((const GLOBAL_AS void*)(aptr + k0 + koff0 * 8),
                                         (LDS_AS void*)(AsB + woff), 16, 0, 0);
        __builtin_amdgcn_global_load_lds((const GLOBAL_AS void*)(aptr + k0 + (koff0 + 2) * 8),
                                         (LDS_AS void*)(AsB + 4096 + woff), 16, 0, 0);
        __builtin_amdgcn_global_load_lds((const GLOBAL_AS void*)(bptr + k0 + koff0 * 8),
                                         (LDS_AS void*)(BsB + woff), 16, 0, 0);
        __builtin_amdgcn_global_load_lds((const GLOBAL_AS void*)(bptr + k0 + (koff0 + 2) * 8),
                                         (LDS_AS void*)(BsB + 4096 + woff), 16, 0, 0);
        __syncthreads();

        short8 av[4], bv[4];
#pragma unroll
        for (int mf = 0; mf < 4; ++mf)
            av[mf] = As8[q * 128 + wm + mf * 16 + r16];
#pragma unroll
        for (int nf = 0; nf < 4; ++nf)
            bv[nf] = Bs8[q * 128 + wn + nf * 16 + r16];
#pragma unroll
        for (int mf = 0; mf < 4; ++mf)
#pragma unroll
            for (int nf = 0; nf < 4; ++nf)
                acc[mf][nf] = __builtin_amdgcn_mfma_f32_16x16x32_bf16(av[mf], bv[nf], acc[mf][nf], 0, 0, 0);
        __syncthreads();
    }

#pragma unroll
    for (int mf = 0; mf < 4; ++mf) {
#pragma unroll
        for (int j = 0; j < 4; ++j) {
            int row = bm + wm + mf * 16 + q * 4 + j;
            if (row >= M) continue;
#pragma unroll
            for (int nf = 0; nf < 4; ++nf) {
                int c = bn + wn + nf * 16 + r16;
                size_t idx = (size_t)row * HID + c;
                float v = fmaxf(acc[mf][nf][j] + bf2f(h_bf[idx]), 0.f);
                h_bf[idx] = f2bf(v);
            }
        }
    }
}

// ---------------- MFMA lin1: out = h @ lin1_w + b ----------------
__global__ __launch_bounds__(256) void lin1_mfma(
        const ushort* __restrict__ h_bf, const ushort* __restrict__ wt1,
        const float* __restrict__ b, float* __restrict__ out, int M) {
    __shared__ ushort As[4][128][8];
    __shared__ ushort Bs[4][128][8];
    int tid = threadIdx.x;
    int wave = tid >> 6;
    int lane = tid & 63;
    int r16 = lane & 15, q = lane >> 4;
    int bm = blockIdx.x * 128;
    int wm = (wave >> 1) * 64, wn = (wave & 1) * 64;

    f32x4 acc[4][4] = {};

    int srow = tid & 127;
    int koff0 = tid >> 7;
    int arow = bm + srow; if (arow >= M) arow = M - 1;
    const ushort* aptr = h_bf + (size_t)arow * HID;
    const ushort* bptr = wt1 + (size_t)srow * HID;
    char* AsB = (char*)&As[0][0][0];
    char* BsB = (char*)&Bs[0][0][0];
    int woff = wave * 1024;

    const short8* As8 = (const short8*)&As[0][0][0];
    const short8* Bs8 = (const short8*)&Bs[0][0][0];

    for (int k0 = 0; k0 < HID; k0 += 32) {
        __builtin_amdgcn_global_load_lds((const GLOBAL_AS void*)(aptr + k0 + koff0 * 8),
                                         (LDS_AS void*)(AsB + woff), 16, 0, 0);
        __builtin_amdgcn_global_load_lds((const GLOBAL_AS void*)(aptr + k0 + (koff0 + 2) * 8),
                                         (LDS_AS void*)(AsB + 4096 + woff), 16, 0, 0);
        __builtin_amdgcn_global_load_lds((const GLOBAL_AS void*)(bptr + k0 + koff0 * 8),
                                         (LDS_AS void*)(BsB + woff), 16, 0, 0);
        __builtin_amdgcn_global_load_lds((const GLOBAL_AS void*)(bptr + k0 + (koff0 + 2) * 8),
                                         (LDS_AS void*)(BsB + 4096 + woff), 16, 0, 0);
        __syncthreads();

        short8 av[4], bv[4];
#pragma unroll
        for (int mf = 0; mf < 4; ++mf)
            av[mf] = As8[q * 128 + wm + mf * 16 + r16];
#pragma unroll
        for (int nf = 0; nf < 4; ++nf)
            bv[nf] = Bs8[q * 128 + wn + nf * 16 + r16];
#pragma unroll
        for (int mf = 0; mf < 4; ++mf)
#pragma unroll
            for (int nf = 0; nf < 4; ++nf)
                acc[mf][nf] = __builtin_amdgcn_mfma_f32_16x16x32_bf16(av[mf], bv[nf], acc[mf][nf], 0, 0, 0);
        __syncthreads();
    }

#pragma unroll
    for (int mf = 0; mf < 4; ++mf) {
#pragma unroll
        for (int j = 0; j < 4; ++j) {
            int row = bm + wm + mf * 16 + q * 4 + j;
            if (row >= M) continue;
#pragma unroll
            for (int nf = 0; nf < 4; ++nf) {
                int c = wn + nf * 16 + r16;
                if (c < OUT_F)
                    out[(size_t)row * OUT_F + c] = acc[mf][nf][j] + b[c];
            }
        }
    }
}

extern "C" void kernel_launch(void* const* d_in, const int* in_sizes, int n_in,
                              void* d_out, int out_size, void* d_ws, size_t ws_size,
                              hipStream_t stream) {
    const float* x      = (const float*)d_in[0];
    const int*   ei     = (const int*)d_in[1];
    const float* ew     = (const float*)d_in[2];
    const float* lin0_w = (const float*)d_in[3];
    const float* lin0_b = (const float*)d_in[4];
    const float* W      = (const float*)d_in[5];
    const float* lin1_w = (const float*)d_in[6];
    const float* lin1_b = (const float*)d_in[7];
    float* out = (float*)d_out;

    int N = in_sizes[0] / IN_F;
    int E = in_sizes[2];
    const int* src = ei;
    const int* dst = ei + E;

    char* ws = (char*)d_ws;
    ushort* x0_bf   = (ushort*)ws; ws += (size_t)N * HID * 2;
    ushort* h_bf    = (ushort*)ws; ws += (size_t)N * HID * 2;
    ushort* s_bf    = (ushort*)ws; ws += (size_t)N * HID * 2;
    ushort* x_bf    = (ushort*)ws; ws += (size_t)N * K0PAD * 2;
    ushort* Wt0     = (ushort*)ws; ws += (size_t)HID * K0PAD * 2;
    ushort* Wt      = (ushort*)ws; ws += (size_t)N_LAYERS * HID * HID * 2;
    ushort* Wt1     = (ushort*)ws; ws += (size_t)128 * HID * 2;
    int*    row_ptr = (int*)ws;    ws += (size_t)(N + 1) * 4;
    int*    counts  = (int*)ws;    ws += (size_t)N * 4;
    int*    cursor  = (int*)ws;    ws += (size_t)N * 4;
    int*    bsum    = (int*)ws;    ws += (size_t)128 * 4;
    int*    col     = (int*)ws;    ws += (size_t)E * 4;
    float*  wv      = (float*)ws;  ws += (size_t)E * 4;

    int nb = (N + 1023) / 1024;

    hipMemsetAsync(counts, 0, (size_t)N * 4, stream);
    hist_kernel<<<(E + 255) / 256, 256, 0, stream>>>(dst, counts, E);
    scan_phase1<<<nb, 1024, 0, stream>>>(counts, row_ptr, bsum, N);
    scan_phase2<<<1, 64, 0, stream>>>(bsum, nb);
    scan_phase3<<<nb, 1024, 0, stream>>>(row_ptr, cursor, bsum, N, nb);
    scatter_kernel<<<(E + 255) / 256, 256, 0, stream>>>(src, dst, ew, cursor, col, wv, E);

    convert_x_kernel<<<(N * K0PAD + 255) / 256, 256, 0, stream>>>(x, x_bf, N);
    convert_w0_kernel<<<HID, K0PAD, 0, stream>>>(lin0_w, Wt0);
    convert_w_kernel<<<dim3(HID, N_LAYERS), HID, 0, stream>>>(W, Wt);
    convert_w1_kernel<<<128, HID, 0, stream>>>(lin1_w, Wt1);

    int mblocks = (N + 127) / 128;
    lin0_mfma<<<dim3(mblocks, 2), 256, 0, stream>>>(x_bf, Wt0, lin0_b, x0_bf, h_bf, N);

    for (int l = 0; l < N_LAYERS; ++l) {
        spmm_mix_kernel<<<(N + 3) / 4, 256, 0, stream>>>(row_ptr, col, wv, h_bf, x0_bf, s_bf, N);
        gemm_mfma_layer<<<dim3(mblocks, 2), 256, 0, stream>>>(
            s_bf, Wt + (size_t)l * HID * HID, h_bf, N);
    }

    lin1_mfma<<<mblocks, 256, 0, stream>>>(h_bf, Wt1, lin1_b, out, N);
}